// Round 5
// baseline (2363.232 us; speedup 1.0000x reference)
//
#include <hip/hip_runtime.h>
#include <stdint.h>

#define L2E 1.4426950408889634f

typedef __attribute__((ext_vector_type(8))) short short8;
typedef __attribute__((ext_vector_type(4))) float floatx4;
typedef __attribute__((ext_vector_type(4))) unsigned int uintx4;
typedef __attribute__((ext_vector_type(2))) _Float16 half2v;

__device__ __forceinline__ uint32_t pkbf(float lo, float hi) {
  uint32_t r;
  asm("v_cvt_pk_bf16_f32 %0, %1, %2" : "=v"(r) : "v"(lo), "v"(hi));
  return r;
}
__device__ __forceinline__ uint32_t pkh(float lo, float hi) {
  uint32_t r;
  asm("v_cvt_pkrtz_f16_f32 %0, %1, %2" : "=v"(r) : "v"(lo), "v"(hi));
  return r;
}
__device__ __forceinline__ float2 uph(uint32_t u) {
  union { uint32_t u; half2v h; } z; z.u = u;
  return make_float2((float)z.h.x, (float)z.h.y);
}
__device__ __forceinline__ short8 mkfrag(const float* p) {
  float4 a = *(const float4*)p;
  float4 b = *(const float4*)(p + 4);
  union { uint32_t u[4]; short8 s; } z;
  z.u[0] = pkbf(a.x, a.y); z.u[1] = pkbf(a.z, a.w);
  z.u[2] = pkbf(b.x, b.y); z.u[3] = pkbf(b.z, b.w);
  return z.s;
}
__device__ __forceinline__ short8 pk8(float4 a, float4 b) {
  union { uint32_t u[4]; short8 s; } z;
  z.u[0] = pkbf(a.x, a.y); z.u[1] = pkbf(a.z, a.w);
  z.u[2] = pkbf(b.x, b.y); z.u[3] = pkbf(b.z, b.w);
  return z.s;
}
__device__ __forceinline__ short8 u4s8(uint32_t a, uint32_t b, uint32_t c, uint32_t d) {
  union { uint32_t u[4]; short8 s; } z;
  z.u[0] = a; z.u[1] = b; z.u[2] = c; z.u[3] = d;
  return z.s;
}

#define SWAP32(a, b) asm("v_permlane32_swap_b32 %0, %1" : "+v"(a), "+v"(b))
#define SWAP16(a, b) asm("v_permlane16_swap_b32 %0, %1" : "+v"(a), "+v"(b))
#define GLDS(gp, lp) __builtin_amdgcn_global_load_lds( \
    (const __attribute__((address_space(1))) void*)(gp), \
    (__attribute__((address_space(3))) void*)(lp), 16, 0, 0)

// ============ G1: preg (f32, slot layout) + mx/m1 (f16, slot layout) ============
__global__ __launch_bounds__(256) void g1_pre(
    const float* __restrict__ values, const float* __restrict__ masks,
    const float* __restrict__ W_ih, const float* __restrict__ b_ih,
    const float* __restrict__ b_hh, float* __restrict__ pregS,
    float* __restrict__ mxm1S, int t0, int gstride)
{
  const int tid = threadIdx.x, wv = tid >> 6, l = tid & 63;
  const int c = l & 15, kw = l >> 4;
  const int tch = blockIdx.x, gr = blockIdx.y;
  const int tbase = t0 + tch * 8;

  short8 WF[8][4];
  #pragma unroll
  for (int tg = 0; tg < 8; ++tg)
    #pragma unroll
    for (int kc = 0; kc < 4; ++kc)
      WF[tg][kc] = mkfrag(W_ih + (size_t)(16*tg + c)*128 + 32*kc + 8*kw);

  float4 bias[8];
  #pragma unroll
  for (int tg = 0; tg < 8; ++tg) {
    float4 bi = *(const float4*)(b_ih + 16*tg + 4*kw);
    float4 bh = *(const float4*)(b_hh + 16*tg + 4*kw);
    bias[tg] = make_float4(bi.x+bh.x, bi.y+bh.y, bi.z+bh.z, bi.w+bh.w);
  }

  #pragma unroll 1
  for (int tt = 0; tt < 2; ++tt) {
    const int lt = wv*2 + tt, t_g = tbase + lt, rec = tch*8 + lt;
    const size_t ibase = ((size_t)(gr*16 + c)*2048 + t_g)*64;
    const float* xr = values + ibase;
    const float* mr = masks + ibase;
    float4 xa0 = *(const float4*)(xr + 8*kw),      xa1 = *(const float4*)(xr + 8*kw + 4);
    float4 xb0 = *(const float4*)(xr + 32 + 8*kw), xb1 = *(const float4*)(xr + 32 + 8*kw + 4);
    float4 ma0 = *(const float4*)(mr + 8*kw),      ma1 = *(const float4*)(mr + 8*kw + 4);
    float4 mb0 = *(const float4*)(mr + 32 + 8*kw), mb1 = *(const float4*)(mr + 32 + 8*kw + 4);
    float4 fa0 = make_float4(xa0.x*ma0.x, xa0.y*ma0.y, xa0.z*ma0.z, xa0.w*ma0.w);
    float4 fa1 = make_float4(xa1.x*ma1.x, xa1.y*ma1.y, xa1.z*ma1.z, xa1.w*ma1.w);
    float4 fb0 = make_float4(xb0.x*mb0.x, xb0.y*mb0.y, xb0.z*mb0.z, xb0.w*mb0.w);
    float4 fb1 = make_float4(xb1.x*mb1.x, xb1.y*mb1.y, xb1.z*mb1.z, xb1.w*mb1.w);

    short8 BF0 = pk8(fa0, fa1), BF1 = pk8(fb0, fb1);
    short8 BF2 = pk8(ma0, ma1), BF3 = pk8(mb0, mb1);

    floatx4 acc[8];
    #pragma unroll
    for (int tg = 0; tg < 8; ++tg) acc[tg] = (floatx4){0.f, 0.f, 0.f, 0.f};
    #pragma unroll
    for (int tg = 0; tg < 8; ++tg) {
      acc[tg] = __builtin_amdgcn_mfma_f32_16x16x32_bf16(WF[tg][0], BF0, acc[tg], 0, 0, 0);
      acc[tg] = __builtin_amdgcn_mfma_f32_16x16x32_bf16(WF[tg][1], BF1, acc[tg], 0, 0, 0);
      acc[tg] = __builtin_amdgcn_mfma_f32_16x16x32_bf16(WF[tg][2], BF2, acc[tg], 0, 0, 0);
      acc[tg] = __builtin_amdgcn_mfma_f32_16x16x32_bf16(WF[tg][3], BF3, acc[tg], 0, 0, 0);
    }

    uint32_t* mm = (uint32_t*)mxm1S + (size_t)(gr*gstride + rec)*1024;
    auto stw = [&](int i, int sect, float lo, float hi) {
      int tl = (i >> 4) & 1, ww = (i & 15) >> 2, jj = 2*tl + ((i >> 1) & 1);
      mm[sect*256 + (c + 16*ww)*4 + jj] = pkh(lo, hi);
    };
    stw(8*kw+0, 0, fa0.x, fa0.y); stw(8*kw+2, 0, fa0.z, fa0.w);
    stw(8*kw+4, 0, fa1.x, fa1.y); stw(8*kw+6, 0, fa1.z, fa1.w);
    stw(32+8*kw+0, 1, fb0.x, fb0.y); stw(32+8*kw+2, 1, fb0.z, fb0.w);
    stw(32+8*kw+4, 1, fb1.x, fb1.y); stw(32+8*kw+6, 1, fb1.z, fb1.w);
    stw(8*kw+0, 2, 1.f-ma0.x, 1.f-ma0.y); stw(8*kw+2, 2, 1.f-ma0.z, 1.f-ma0.w);
    stw(8*kw+4, 2, 1.f-ma1.x, 1.f-ma1.y); stw(8*kw+6, 2, 1.f-ma1.z, 1.f-ma1.w);
    stw(32+8*kw+0, 3, 1.f-mb0.x, 1.f-mb0.y); stw(32+8*kw+2, 3, 1.f-mb0.z, 1.f-mb0.w);
    stw(32+8*kw+4, 3, 1.f-mb1.x, 1.f-mb1.y); stw(32+8*kw+6, 3, 1.f-mb1.z, 1.f-mb1.w);

    float4* pf = (float4*)pregS + (size_t)(gr*gstride + rec)*512 + (c + 16*kw);
    #pragma unroll
    for (int tg = 0; tg < 8; ++tg)
      pf[tg*64] = make_float4(acc[tg][0]+bias[tg].x, acc[tg][1]+bias[tg].y,
                              acc[tg][2]+bias[tg].z, acc[tg][3]+bias[tg].w);
  }
}

// ============ G2: gamma (f16, slot layout) ============
__global__ __launch_bounds__(256) void g2_gam(
    const float* __restrict__ deltas, const float* __restrict__ W_decay,
    const float* __restrict__ b_decay, float* __restrict__ gamS,
    int t0, int gstride)
{
  const int tid = threadIdx.x, wv = tid >> 6, l = tid & 63;
  const int c = l & 15, kw = l >> 4;
  const int tch = blockIdx.x, gr = blockIdx.y;
  const int tbase = t0 + tch * 8;

  short8 AF[2][2];
  #pragma unroll
  for (int jt = 0; jt < 2; ++jt)
    #pragma unroll
    for (int kc = 0; kc < 2; ++kc)
      AF[jt][kc] = mkfrag(W_decay + (size_t)(16*jt + c)*64 + 32*kc + 8*kw);
  float4 bd0 = *(const float4*)(b_decay + 4*kw);
  float4 bd1 = *(const float4*)(b_decay + 16 + 4*kw);

  #pragma unroll 1
  for (int tt = 0; tt < 2; ++tt) {
    const int lt = wv*2 + tt, t_g = tbase + lt, rec = tch*8 + lt;
    const float* dr = deltas + ((size_t)(gr*16 + c)*2048 + t_g)*64;
    float4 da0 = *(const float4*)(dr + 8*kw),      da1 = *(const float4*)(dr + 8*kw + 4);
    float4 db0 = *(const float4*)(dr + 32 + 8*kw), db1 = *(const float4*)(dr + 32 + 8*kw + 4);
    short8 B0 = pk8(da0, da1), B1 = pk8(db0, db1);
    floatx4 zz = (floatx4){0.f, 0.f, 0.f, 0.f};
    floatx4 a0 = __builtin_amdgcn_mfma_f32_16x16x32_bf16(AF[0][0], B0, zz, 0, 0, 0);
    a0 = __builtin_amdgcn_mfma_f32_16x16x32_bf16(AF[0][1], B1, a0, 0, 0, 0);
    floatx4 a1 = __builtin_amdgcn_mfma_f32_16x16x32_bf16(AF[1][0], B0, zz, 0, 0, 0);
    a1 = __builtin_amdgcn_mfma_f32_16x16x32_bf16(AF[1][1], B1, a1, 0, 0, 0);
    float g0 = __builtin_amdgcn_exp2f(-fmaxf(a0[0]+bd0.x, 0.f) * L2E);
    float g1 = __builtin_amdgcn_exp2f(-fmaxf(a0[1]+bd0.y, 0.f) * L2E);
    float g2 = __builtin_amdgcn_exp2f(-fmaxf(a0[2]+bd0.z, 0.f) * L2E);
    float g3 = __builtin_amdgcn_exp2f(-fmaxf(a0[3]+bd0.w, 0.f) * L2E);
    float h0 = __builtin_amdgcn_exp2f(-fmaxf(a1[0]+bd1.x, 0.f) * L2E);
    float h1 = __builtin_amdgcn_exp2f(-fmaxf(a1[1]+bd1.y, 0.f) * L2E);
    float h2 = __builtin_amdgcn_exp2f(-fmaxf(a1[2]+bd1.z, 0.f) * L2E);
    float h3 = __builtin_amdgcn_exp2f(-fmaxf(a1[3]+bd1.w, 0.f) * L2E);
    uintx4 o = (uintx4){pkh(g0, g1), pkh(g2, g3), pkh(h0, h1), pkh(h2, h3)};
    ((uintx4*)gamS)[(size_t)(gr*gstride + rec)*64 + c + 16*kw] = o;
  }
}

// ============ P5: MFMA recurrence, global_load_lds ring + counted vmcnt ============
#define PW(GI, GF, GG, GO, CC, HH) do { \
  float _si = __builtin_amdgcn_rcpf(1.f + __builtin_amdgcn_exp2f((GI) * -L2E)); \
  float _sf = __builtin_amdgcn_rcpf(1.f + __builtin_amdgcn_exp2f((GF) * -L2E)); \
  float _so = __builtin_amdgcn_rcpf(1.f + __builtin_amdgcn_exp2f((GO) * -L2E)); \
  float _tg = 1.f - 2.f*__builtin_amdgcn_rcpf(1.f + __builtin_amdgcn_exp2f((GG) * (2.f*L2E))); \
  float _cn = fmaf(_sf, (CC), _si*_tg); \
  float _tc = 1.f - 2.f*__builtin_amdgcn_rcpf(1.f + __builtin_amdgcn_exp2f(_cn * (2.f*L2E))); \
  (CC) = _cn; (HH) = _so * _tc; \
} while (0)

#define SLOTB 13312

__global__ __launch_bounds__(64, 1) void p5_rnn(
    const float* __restrict__ W_hh, const float* __restrict__ W_reg,
    const float* __restrict__ W_ih, const float* __restrict__ b_reg,
    const float* __restrict__ W_out, const float* __restrict__ b_out,
    const float* __restrict__ pregS, const float* __restrict__ gamS,
    const float* __restrict__ mxm1S,
    float* __restrict__ hc, float* __restrict__ y, float* __restrict__ imp,
    int t0, int ns, int gstride)
{
  const int l = threadIdx.x, gr = blockIdx.x;
  const int b = l & 15, w = l >> 4;
  __shared__ __align__(16) char ring[4 * SLOTB];

  short8 WhhA[8], WxcA0[8], WxcA1[8], WregA[4];
  #pragma unroll
  for (int t = 0; t < 8; ++t) {
    WhhA[t]  = mkfrag(W_hh + (size_t)(16*t + b)*32 + 8*w);
    WxcA0[t] = mkfrag(W_ih + (size_t)(16*t + b)*128 + 8*w);
    WxcA1[t] = mkfrag(W_ih + (size_t)(16*t + b)*128 + 32 + 8*w);
  }
  #pragma unroll
  for (int t = 0; t < 4; ++t) WregA[t] = mkfrag(W_reg + (size_t)(16*t + b)*32 + 8*w);
  floatx4 brC[4];
  #pragma unroll
  for (int t = 0; t < 4; ++t) {
    float4 v = *(const float4*)(b_reg + 16*t + 4*w);
    brC[t] = (floatx4){v.x, v.y, v.z, v.w};
  }

  float4 h0, h1, cv0, cv1;
  if (t0 == 0) {
    h0 = h1 = cv0 = cv1 = make_float4(0.f, 0.f, 0.f, 0.f);
  } else {
    const float* hp = hc + ((size_t)gr*64 + l)*16;
    h0  = *(const float4*)(hp);
    h1  = *(const float4*)(hp + 4);
    cv0 = *(const float4*)(hp + 8);
    cv1 = *(const float4*)(hp + 12);
  }

  const char* pregB = (const char*)pregS + (size_t)gr*gstride*8192 + (size_t)l*16;
  const char* gamB  = (const char*)gamS  + (size_t)gr*gstride*1024 + (size_t)l*16;
  const char* mmB   = (const char*)mxm1S + (size_t)gr*gstride*4096 + (size_t)l*16;
  float* impP = imp + ((size_t)(gr*16 + b)*2048 + t0)*64 + 4*w;

  floatx4 PRA[8], PRB[8];
  uintx4 GMA, GMB, MXA[2], MXB[2], M1A[2], M1B[2];

  auto PREFL = [&](int rec, int slot) {
    const char* pb = pregB + (size_t)rec*8192;
    char* sb = ring + slot*SLOTB;
    #pragma unroll
    for (int t = 0; t < 8; ++t) GLDS(pb + t*1024, sb + t*1024);
    GLDS(gamB + (size_t)rec*1024, sb + 8192);
    const char* mb = mmB + (size_t)rec*4096;
    #pragma unroll
    for (int c4 = 0; c4 < 4; ++c4) GLDS(mb + c4*1024, sb + 9216 + c4*1024);
  };

  auto DSRD = [&](int slot, floatx4 (&PR)[8], uintx4& GM, uintx4 (&MX)[2], uintx4 (&M1)[2]) {
    const char* sb = ring + slot*SLOTB + (size_t)l*16;
    #pragma unroll
    for (int t = 0; t < 8; ++t) PR[t] = *(const floatx4*)(sb + t*1024);
    GM = *(const uintx4*)(sb + 8192);
    MX[0] = *(const uintx4*)(sb + 9216);
    MX[1] = *(const uintx4*)(sb + 9216 + 1024);
    M1[0] = *(const uintx4*)(sb + 9216 + 2048);
    M1[1] = *(const uintx4*)(sb + 9216 + 3072);
  };

  auto BODY = [&](floatx4 (&PR)[8], uintx4& GM, uintx4 (&MX)[2], uintx4 (&M1)[2]) {
    float2 gA = uph(GM[0]), gB = uph(GM[1]);
    float2 gC = uph(GM[2]), gD = uph(GM[3]);
    float4 hd0 = make_float4(h0.x*gA.x, h0.y*gA.y, h0.z*gB.x, h0.w*gB.y);
    float4 hd1 = make_float4(h1.x*gC.x, h1.y*gC.y, h1.z*gD.x, h1.w*gD.y);
    uint32_t P0 = pkbf(hd0.x, hd0.y), P1 = pkbf(hd0.z, hd0.w);
    uint32_t Q0 = pkbf(hd1.x, hd1.y), Q1 = pkbf(hd1.z, hd1.w);
    SWAP32(P0, Q0); SWAP32(P1, Q1);
    SWAP16(P0, Q0); SWAP16(P1, Q1);
    short8 Bhd = u4s8(P0, P1, Q0, Q1);

    floatx4 uu[4];
    #pragma unroll
    for (int t = 0; t < 4; ++t)
      uu[t] = __builtin_amdgcn_mfma_f32_16x16x32_bf16(WregA[t], Bhd, brC[t], 0, 0, 0);
    floatx4 ga[8];
    #pragma unroll
    for (int t = 0; t < 8; ++t)
      ga[t] = __builtin_amdgcn_mfma_f32_16x16x32_bf16(WhhA[t], Bhd, PR[t], 0, 0, 0);

    uint32_t U[8];
    #pragma unroll
    for (int t = 0; t < 4; ++t) {
      float2 m1a = uph(M1[t>>1][2*(t&1)]), m1b = uph(M1[t>>1][2*(t&1)+1]);
      float2 mxa = uph(MX[t>>1][2*(t&1)]), mxb = uph(MX[t>>1][2*(t&1)+1]);
      float v0 = m1a.x*uu[t][0], v1 = m1a.y*uu[t][1];
      float v2 = m1b.x*uu[t][2], v3 = m1b.y*uu[t][3];
      *(float4*)(impP + 16*t) = make_float4(v0+mxa.x, v1+mxa.y, v2+mxb.x, v3+mxb.y);
      U[2*t]   = pkbf(v0, v1);
      U[2*t+1] = pkbf(v2, v3);
    }
    SWAP32(U[0], U[2]); SWAP32(U[1], U[3]);
    SWAP16(U[0], U[2]); SWAP16(U[1], U[3]);
    short8 Bv0 = u4s8(U[0], U[1], U[2], U[3]);
    SWAP32(U[4], U[6]); SWAP32(U[5], U[7]);
    SWAP16(U[4], U[6]); SWAP16(U[5], U[7]);
    short8 Bv1 = u4s8(U[4], U[5], U[6], U[7]);

    #pragma unroll
    for (int t = 0; t < 8; ++t)
      ga[t] = __builtin_amdgcn_mfma_f32_16x16x32_bf16(WxcA0[t], Bv0, ga[t], 0, 0, 0);
    #pragma unroll
    for (int t = 0; t < 8; ++t)
      ga[t] = __builtin_amdgcn_mfma_f32_16x16x32_bf16(WxcA1[t], Bv1, ga[t], 0, 0, 0);
    impP += 64;

    PW(ga[0][0], ga[2][0], ga[4][0], ga[6][0], cv0.x, h0.x);
    PW(ga[0][1], ga[2][1], ga[4][1], ga[6][1], cv0.y, h0.y);
    PW(ga[0][2], ga[2][2], ga[4][2], ga[6][2], cv0.z, h0.z);
    PW(ga[0][3], ga[2][3], ga[4][3], ga[6][3], cv0.w, h0.w);
    PW(ga[1][0], ga[3][0], ga[5][0], ga[7][0], cv1.x, h1.x);
    PW(ga[1][1], ga[3][1], ga[5][1], ga[7][1], cv1.y, h1.y);
    PW(ga[1][2], ga[3][2], ga[5][2], ga[7][2], cv1.z, h1.z);
    PW(ga[1][3], ga[3][3], ga[5][3], ga[7][3], cv1.w, h1.w);
  };

  // prologue: fill 3 slots, drain, read step 0 into reg slot A
  PREFL(0, 0); PREFL(1, 1); PREFL(2, 2);
  asm volatile("s_waitcnt vmcnt(0)" ::: "memory");
  DSRD(0, PRA, GMA, MXA, M1A);

  #pragma unroll 1
  for (int j = 0; j < ns; j += 2) {
    PREFL(j + 3, (j + 3) & 3);
    asm volatile("s_waitcnt vmcnt(26)" ::: "memory");
    DSRD((j + 1) & 3, PRB, GMB, MXB, M1B);
    BODY(PRA, GMA, MXA, M1A);
    PREFL(j + 4, (j + 4) & 3);
    asm volatile("s_waitcnt vmcnt(26)" ::: "memory");
    DSRD((j + 2) & 3, PRA, GMA, MXA, M1A);
    BODY(PRB, GMB, MXB, M1B);
  }

  if (t0 + ns < 2048) {
    float* hp = hc + ((size_t)gr*64 + l)*16;
    *(float4*)(hp)      = h0;
    *(float4*)(hp + 4)  = h1;
    *(float4*)(hp + 8)  = cv0;
    *(float4*)(hp + 12) = cv1;
  } else {
    auto d4 = [](float4 a, float4 bb) {
      return fmaf(a.x, bb.x, fmaf(a.y, bb.y, fmaf(a.z, bb.z, a.w*bb.w)));
    };
    float4 wo00 = *(const float4*)(W_out + 4*w);
    float4 wo01 = *(const float4*)(W_out + 16 + 4*w);
    float4 wo10 = *(const float4*)(W_out + 32 + 4*w);
    float4 wo11 = *(const float4*)(W_out + 48 + 4*w);
    float p0 = d4(h0, wo00) + d4(h1, wo01);
    float p1 = d4(h0, wo10) + d4(h1, wo11);
    p0 += __shfl_xor(p0, 16); p0 += __shfl_xor(p0, 32);
    p1 += __shfl_xor(p1, 16); p1 += __shfl_xor(p1, 32);
    if (l < 16) {
      y[(gr*16 + l)*2 + 0] = p0 + b_out[0];
      y[(gr*16 + l)*2 + 1] = p1 + b_out[1];
    }
  }
}

extern "C" void kernel_launch(void* const* d_in, const int* in_sizes, int n_in,
                              void* d_out, int out_size, void* d_ws, size_t ws_size,
                              hipStream_t stream) {
  (void)in_sizes; (void)n_in; (void)out_size;
  const float* values  = (const float*)d_in[0];
  const float* masks   = (const float*)d_in[1];
  const float* deltas  = (const float*)d_in[2];
  const float* W_decay = (const float*)d_in[3];
  const float* b_decay = (const float*)d_in[4];
  const float* W_reg   = (const float*)d_in[5];
  const float* b_reg   = (const float*)d_in[6];
  const float* W_ih    = (const float*)d_in[7];
  const float* b_ih    = (const float*)d_in[8];
  const float* W_hh    = (const float*)d_in[9];
  const float* b_hh    = (const float*)d_in[10];
  const float* W_out   = (const float*)d_in[11];
  const float* b_out   = (const float*)d_in[12];
  float* y   = (float*)d_out;
  float* imp = (float*)d_out + 512;   // outputs: y [256,2] then imputations [256,2048,64]

  // ws: hc[64KB] | preg f32 | gam f16 | mxm1 f16  (13312 B per (group,step))
  int SEG = 2048;
  while (SEG > 32) {
    size_t need = 65536ull + 16ull*(size_t)(SEG + 8)*13312ull;
    if (need <= ws_size) break;
    SEG >>= 1;
  }
  const int gstride = SEG + 8;

  float* hcW   = (float*)d_ws;
  float* pregS = (float*)((char*)d_ws + 65536);
  float* gamS  = pregS + (size_t)16*gstride*2048;
  float* mxm1S = gamS  + (size_t)16*gstride*256;

  for (int t0 = 0; t0 < 2048; t0 += SEG) {
    dim3 gg(SEG/8, 16);
    hipLaunchKernelGGL(g1_pre, gg, dim3(256), 0, stream,
                       values, masks, W_ih, b_ih, b_hh, pregS, mxm1S, t0, gstride);
    hipLaunchKernelGGL(g2_gam, gg, dim3(256), 0, stream,
                       deltas, W_decay, b_decay, gamS, t0, gstride);
    hipLaunchKernelGGL(p5_rnn, dim3(16), dim3(64), 0, stream,
                       W_hh, W_reg, W_ih, b_reg, W_out, b_out,
                       pregS, gamS, mxm1S, hcW, y, imp, t0, SEG, gstride);
  }
}